// Round 1
// baseline (648.206 us; speedup 1.0000x reference)
//
#include <hip/hip_runtime.h>
#include <cstddef>

#define BATCH 32
#define EMBD 1024
#define SCTX 1023   // cached positions
#define CTXF 1024   // full context after concat
#define HIDD 4096
#define VOC 65535

// ---------------- embed: x[b] = emb[idx[b]] + pos[0] ----------------
__global__ void embed_kernel(const int* __restrict__ idx, const float* __restrict__ emb,
                             const float* __restrict__ pos, float* __restrict__ x) {
  int b = blockIdx.x, t = threadIdx.x;  // 32 blocks x 256
  const float4* er = (const float4*)(emb + (size_t)idx[b] * EMBD);
  const float4* pr = (const float4*)pos;
  float4 e = er[t], p = pr[t];
  ((float4*)(x + (size_t)b * EMBD))[t] = make_float4(e.x + p.x, e.y + p.y, e.z + p.z, e.w + p.w);
}

// ---------------- split-K skinny GEMM: partials[p][b][j] = sum_{i in chunk} X[b][i] * W[i][j] ----
__global__ void skgemm_qkv(const float* __restrict__ X,
                           const float* __restrict__ Wk, const float* __restrict__ Wv,
                           const float* __restrict__ Wq,
                           float* __restrict__ Pout /* [3][8][32][1024] */) {
  const float* __restrict__ W = (blockIdx.z == 0) ? Wk : (blockIdx.z == 1) ? Wv : Wq;
  int j = blockIdx.x * 256 + threadIdx.x;       // grid.x = 4
  int p = blockIdx.y;                           // 8 chunks of 128
  float acc[BATCH];
#pragma unroll
  for (int b = 0; b < BATCH; ++b) acc[b] = 0.f;
  int i0 = p * 128;
#pragma unroll 4
  for (int i = i0; i < i0 + 128; ++i) {
    float w = W[(size_t)i * EMBD + j];
#pragma unroll
    for (int b = 0; b < BATCH; ++b) acc[b] = fmaf(X[b * EMBD + i], w, acc[b]);
  }
#pragma unroll
  for (int b = 0; b < BATCH; ++b)
    Pout[((size_t)(blockIdx.z * 8 + p) * BATCH + b) * EMBD + j] = acc[b];
}

__global__ void reduce_qkv(const float* __restrict__ part,
                           const float* __restrict__ bk, const float* __restrict__ bv,
                           const float* __restrict__ bq,
                           float* __restrict__ kout, float* __restrict__ vout,
                           float* __restrict__ qout) {
  int z = blockIdx.y;
  int m = blockIdx.x * 256 + threadIdx.x;       // < 32768
  float s = 0.f;
#pragma unroll
  for (int p = 0; p < 8; ++p) s += part[(size_t)(z * 8 + p) * (BATCH * EMBD) + m];
  const float* bias = (z == 0) ? bk : (z == 1) ? bv : bq;
  float* out = (z == 0) ? kout : (z == 1) ? vout : qout;
  out[m] = s + bias[m & (EMBD - 1)];
}

template <int BB>
__global__ void skgemm(const float* __restrict__ X, const float* __restrict__ W,
                       float* __restrict__ Pout, int N, int K, int chunk) {
  int j = blockIdx.x * 256 + threadIdx.x;
  int p = blockIdx.y;
  float acc[BB];
#pragma unroll
  for (int b = 0; b < BB; ++b) acc[b] = 0.f;
  int i0 = p * chunk, i1 = i0 + chunk;
#pragma unroll 4
  for (int i = i0; i < i1; ++i) {
    float w = W[(size_t)i * N + j];
#pragma unroll
    for (int b = 0; b < BB; ++b) acc[b] = fmaf(X[b * K + i], w, acc[b]);
  }
#pragma unroll
  for (int b = 0; b < BB; ++b) Pout[((size_t)p * BB + b) * N + j] = acc[b];
}

// out[m] = act( sum_p part[p][m] + bias[m & mask] )
__global__ void reduce_ep(const float* __restrict__ part, int P,
                          const float* __restrict__ bias, float* __restrict__ out,
                          int total, int mask, int act) {
  int m = blockIdx.x * 256 + threadIdx.x;
  if (m >= total) return;
  float s = 0.f;
  for (int p = 0; p < P; ++p) s += part[(size_t)p * total + m];
  if (bias) s += bias[m & mask];
  if (act == 1) s = 0.5f * s * (1.f + erff(s * 0.70710678118654752f));
  out[m] = s;
}

// ---------------- attention ----------------
__global__ void scores_kernel(const float* __restrict__ q, const float* __restrict__ kcache,
                              const float* __restrict__ knew, float* __restrict__ scores) {
  int b = blockIdx.y;
  int wave = threadIdx.x >> 6, lane = threadIdx.x & 63;
  const float* qb = q + (size_t)b * EMBD;
  float4 qf[4];
#pragma unroll
  for (int r = 0; r < 4; ++r) qf[r] = *(const float4*)(qb + r * 256 + lane * 4);
  for (int it = 0; it < 8; ++it) {
    int s = blockIdx.x * 32 + wave * 8 + it;
    const float* krow = (s < SCTX) ? (kcache + ((size_t)b * SCTX + s) * EMBD)
                                   : (knew + (size_t)b * EMBD);
    float acc = 0.f;
#pragma unroll
    for (int r = 0; r < 4; ++r) {
      float4 kf = *(const float4*)(krow + r * 256 + lane * 4);
      acc += qf[r].x * kf.x + qf[r].y * kf.y + qf[r].z * kf.z + qf[r].w * kf.w;
    }
#pragma unroll
    for (int m = 32; m > 0; m >>= 1) acc += __shfl_xor(acc, m, 64);
    if (lane == 0) scores[(size_t)b * CTXF + s] = acc * 0.03125f;  // 1/sqrt(1024)
  }
}

__global__ void softmax_kernel(float* __restrict__ sc) {
  int b = blockIdx.x;
  int t = threadIdx.x;  // 1024
  __shared__ float red[16];
  float v = sc[(size_t)b * CTXF + t];
  float m = v;
#pragma unroll
  for (int d = 32; d > 0; d >>= 1) m = fmaxf(m, __shfl_xor(m, d, 64));
  if ((t & 63) == 0) red[t >> 6] = m;
  __syncthreads();
  float bm = red[0];
#pragma unroll
  for (int w = 1; w < 16; ++w) bm = fmaxf(bm, red[w]);
  float e = expf(v - bm);
  __syncthreads();
  float s = e;
#pragma unroll
  for (int d = 32; d > 0; d >>= 1) s += __shfl_xor(s, d, 64);
  if ((t & 63) == 0) red[t >> 6] = s;
  __syncthreads();
  float bs = 0.f;
#pragma unroll
  for (int w = 0; w < 16; ++w) bs += red[w];
  sc[(size_t)b * CTXF + t] = e / bs;
}

__global__ void pv_kernel(const float* __restrict__ probs, const float* __restrict__ vcache,
                          const float* __restrict__ vnew, float* __restrict__ part) {
  int b = blockIdx.y;   // 32
  int p = blockIdx.x;   // 8 chunks of 128 rows
  int t = threadIdx.x;  // 256
  float acc[4] = {0.f, 0.f, 0.f, 0.f};
  int s0 = p * 128;
  for (int s = s0; s < s0 + 128; ++s) {
    float pr = probs[(size_t)b * CTXF + s];
    const float* vrow = (s < SCTX) ? (vcache + ((size_t)b * SCTX + s) * EMBD)
                                   : (vnew + (size_t)b * EMBD);
#pragma unroll
    for (int r = 0; r < 4; ++r) acc[r] = fmaf(pr, vrow[t + r * 256], acc[r]);
  }
#pragma unroll
  for (int r = 0; r < 4; ++r) part[((size_t)p * BATCH + b) * EMBD + t + r * 256] = acc[r];
}

// ---------------- logits: out[b][v] = sum_i ffn[b][i] * Wl[i][v] + bl[v] ----------------
__global__ void logits_kernel(const float* __restrict__ X, const float* __restrict__ Wl,
                              const float* __restrict__ bl, float* __restrict__ out) {
  int j = blockIdx.x * 256 + threadIdx.x;
  if (j >= VOC) return;
  float acc[BATCH];
#pragma unroll
  for (int b = 0; b < BATCH; ++b) acc[b] = 0.f;
#pragma unroll 4
  for (int i = 0; i < EMBD; ++i) {
    float w = Wl[(size_t)i * VOC + j];
#pragma unroll
    for (int b = 0; b < BATCH; ++b) acc[b] = fmaf(X[b * EMBD + i], w, acc[b]);
  }
  float bb = bl[j];
#pragma unroll
  for (int b = 0; b < BATCH; ++b) out[(size_t)b * VOC + j] = acc[b] + bb;
}

extern "C" void kernel_launch(void* const* d_in, const int* in_sizes, int n_in,
                              void* d_out, int out_size, void* d_ws, size_t ws_size,
                              hipStream_t stream) {
  const int* idx = (const int*)d_in[0];
  const float* key_cache = (const float*)d_in[1];
  const float* value_cache = (const float*)d_in[2];
  const float* emb_table = (const float*)d_in[3];
  const float* pos_table = (const float*)d_in[4];
  const float* Wk = (const float*)d_in[5];
  const float* bk = (const float*)d_in[6];
  const float* Wv = (const float*)d_in[7];
  const float* bv = (const float*)d_in[8];
  const float* Wq = (const float*)d_in[9];
  const float* bq = (const float*)d_in[10];
  const float* W1 = (const float*)d_in[11];
  const float* b1 = (const float*)d_in[12];
  const float* W2 = (const float*)d_in[13];
  const float* b2 = (const float*)d_in[14];
  const float* Wl = (const float*)d_in[15];
  const float* bl = (const float*)d_in[16];
  float* out = (float*)d_out;

  float* ws = (float*)d_ws;
  float* x    = ws;                    // 32768
  float* k    = ws + 32768;            // 32768
  float* v    = ws + 65536;            // 32768
  float* q    = ws + 98304;            // 32768
  float* prob = ws + 131072;           // 32768 (scores -> probs in place)
  float* attn = ws + 163840;           // 32768
  float* h    = ws + 196608;           // 131072
  float* ffn  = ws + 327680;           // 32768
  float* part = ws + 360448;           // up to 1048576

  embed_kernel<<<dim3(BATCH), 256, 0, stream>>>(idx, emb_table, pos_table, x);

  skgemm_qkv<<<dim3(4, 8, 3), 256, 0, stream>>>(x, Wk, Wv, Wq, part);
  reduce_qkv<<<dim3(128, 3), 256, 0, stream>>>(part, bk, bv, bq, k, v, q);

  scores_kernel<<<dim3(32, BATCH), 256, 0, stream>>>(q, key_cache, k, prob);
  softmax_kernel<<<dim3(BATCH), 1024, 0, stream>>>(prob);
  pv_kernel<<<dim3(8, BATCH), 256, 0, stream>>>(prob, value_cache, v, part);
  reduce_ep<<<dim3(128), 256, 0, stream>>>(part, 8, nullptr, attn, BATCH * EMBD, 0, 0);

  skgemm<BATCH><<<dim3(16, 8), 256, 0, stream>>>(attn, W1, part, HIDD, EMBD, 128);
  reduce_ep<<<dim3(512), 256, 0, stream>>>(part, 8, b1, h, BATCH * HIDD, HIDD - 1, 1);

  skgemm<BATCH><<<dim3(4, 32), 256, 0, stream>>>(h, W2, part, EMBD, HIDD, 128);
  reduce_ep<<<dim3(128), 256, 0, stream>>>(part, 32, b2, ffn, BATCH * EMBD, EMBD - 1, 0);

  logits_kernel<<<dim3(256), 256, 0, stream>>>(ffn, Wl, bl, out);
}

// Round 2
// 378.166 us; speedup vs baseline: 1.7141x; 1.7141x over previous
//
#include <hip/hip_runtime.h>
#include <cstddef>

#define BATCH 32
#define EMBD 1024
#define SCTX 1023   // cached positions
#define CTXF 1024   // full context after concat
#define HIDD 4096
#define VOC 65535

// ---------------- embed: x[b] = emb[idx[b]] + pos[0] ----------------
__global__ void embed_kernel(const int* __restrict__ idx, const float* __restrict__ emb,
                             const float* __restrict__ pos, float* __restrict__ x) {
  int b = blockIdx.x, t = threadIdx.x;  // 32 blocks x 256
  const float4* er = (const float4*)(emb + (size_t)idx[b] * EMBD);
  const float4* pr = (const float4*)pos;
  float4 e = er[t], p = pr[t];
  ((float4*)(x + (size_t)b * EMBD))[t] = make_float4(e.x + p.x, e.y + p.y, e.z + p.z, e.w + p.w);
}

// ---------------- split-K skinny GEMM for QKV ----------------
__global__ void skgemm_qkv(const float* __restrict__ X,
                           const float* __restrict__ Wk, const float* __restrict__ Wv,
                           const float* __restrict__ Wq,
                           float* __restrict__ Pout, int chunk) {
  const float* __restrict__ W = (blockIdx.z == 0) ? Wk : (blockIdx.z == 1) ? Wv : Wq;
  int j = blockIdx.x * 256 + threadIdx.x;       // grid.x = 4
  int p = blockIdx.y;
  int nch = gridDim.y;
  float acc[BATCH];
#pragma unroll
  for (int b = 0; b < BATCH; ++b) acc[b] = 0.f;
  int i0 = p * chunk;
#pragma unroll 8
  for (int i = i0; i < i0 + chunk; ++i) {
    float w = W[(size_t)i * EMBD + j];
#pragma unroll
    for (int b = 0; b < BATCH; ++b) acc[b] = fmaf(X[b * EMBD + i], w, acc[b]);
  }
#pragma unroll
  for (int b = 0; b < BATCH; ++b)
    Pout[((size_t)(blockIdx.z * nch + p) * BATCH + b) * EMBD + j] = acc[b];
}

__global__ void reduce_qkv(const float* __restrict__ part, int P,
                           const float* __restrict__ bk, const float* __restrict__ bv,
                           const float* __restrict__ bq,
                           float* __restrict__ kout, float* __restrict__ vout,
                           float* __restrict__ qout) {
  int z = blockIdx.y;
  int m = blockIdx.x * 256 + threadIdx.x;       // < 32768
  float s = 0.f;
  for (int p = 0; p < P; ++p) s += part[(size_t)(z * P + p) * (BATCH * EMBD) + m];
  const float* bias = (z == 0) ? bk : (z == 1) ? bv : bq;
  float* out = (z == 0) ? kout : (z == 1) ? vout : qout;
  out[m] = s + bias[m & (EMBD - 1)];
}

template <int BB>
__global__ void skgemm(const float* __restrict__ X, const float* __restrict__ W,
                       float* __restrict__ Pout, int N, int K, int chunk) {
  int j = blockIdx.x * 256 + threadIdx.x;
  int p = blockIdx.y;
  float acc[BB];
#pragma unroll
  for (int b = 0; b < BB; ++b) acc[b] = 0.f;
  int i0 = p * chunk, i1 = i0 + chunk;
#pragma unroll 8
  for (int i = i0; i < i1; ++i) {
    float w = W[(size_t)i * N + j];
#pragma unroll
    for (int b = 0; b < BB; ++b) acc[b] = fmaf(X[b * K + i], w, acc[b]);
  }
#pragma unroll
  for (int b = 0; b < BB; ++b) Pout[((size_t)p * BB + b) * N + j] = acc[b];
}

// out[m] = act( sum_p part[p][m] + bias[m & mask] )
__global__ void reduce_ep(const float* __restrict__ part, int P,
                          const float* __restrict__ bias, float* __restrict__ out,
                          int total, int mask, int act) {
  int m = blockIdx.x * 256 + threadIdx.x;
  if (m >= total) return;
  float s = 0.f;
  for (int p = 0; p < P; ++p) s += part[(size_t)p * total + m];
  if (bias) s += bias[m & mask];
  if (act == 1) s = 0.5f * s * (1.f + erff(s * 0.70710678118654752f));
  out[m] = s;
}

// ---------------- attention ----------------
// grid (64, 32): block = 4 waves, each wave computes 4 score rows concurrently
__global__ void scores_kernel(const float* __restrict__ q, const float* __restrict__ kcache,
                              const float* __restrict__ knew, float* __restrict__ scores) {
  int b = blockIdx.y;
  int wave = threadIdx.x >> 6, lane = threadIdx.x & 63;
  const float* qb = q + (size_t)b * EMBD;
  float4 qf[4];
#pragma unroll
  for (int r = 0; r < 4; ++r) qf[r] = *(const float4*)(qb + r * 256 + lane * 4);
  int sbase = blockIdx.x * 16 + wave * 4;
  const float* kr[4];
  float acc[4] = {0.f, 0.f, 0.f, 0.f};
#pragma unroll
  for (int it = 0; it < 4; ++it) {
    int s = sbase + it;
    kr[it] = (s < SCTX) ? (kcache + ((size_t)b * SCTX + s) * EMBD)
                        : (knew + (size_t)b * EMBD);
  }
#pragma unroll
  for (int r = 0; r < 4; ++r) {
#pragma unroll
    for (int it = 0; it < 4; ++it) {
      float4 kf = *(const float4*)(kr[it] + r * 256 + lane * 4);
      acc[it] += qf[r].x * kf.x + qf[r].y * kf.y + qf[r].z * kf.z + qf[r].w * kf.w;
    }
  }
#pragma unroll
  for (int it = 0; it < 4; ++it) {
    float a = acc[it];
#pragma unroll
    for (int m = 32; m > 0; m >>= 1) a += __shfl_xor(a, m, 64);
    if (lane == 0) scores[(size_t)b * CTXF + sbase + it] = a * 0.03125f;  // 1/sqrt(1024)
  }
}

__global__ void softmax_kernel(float* __restrict__ sc) {
  int b = blockIdx.x;
  int t = threadIdx.x;  // 1024
  __shared__ float red[16];
  float v = sc[(size_t)b * CTXF + t];
  float m = v;
#pragma unroll
  for (int d = 32; d > 0; d >>= 1) m = fmaxf(m, __shfl_xor(m, d, 64));
  if ((t & 63) == 0) red[t >> 6] = m;
  __syncthreads();
  float bm = red[0];
#pragma unroll
  for (int w = 1; w < 16; ++w) bm = fmaxf(bm, red[w]);
  float e = expf(v - bm);
  __syncthreads();
  float s = e;
#pragma unroll
  for (int d = 32; d > 0; d >>= 1) s += __shfl_xor(s, d, 64);
  if ((t & 63) == 0) red[t >> 6] = s;
  __syncthreads();
  float bs = 0.f;
#pragma unroll
  for (int w = 0; w < 16; ++w) bs += red[w];
  sc[(size_t)b * CTXF + t] = e / bs;
}

// grid (32, 32): 32 chunks of 32 rows
__global__ void pv_kernel(const float* __restrict__ probs, const float* __restrict__ vcache,
                          const float* __restrict__ vnew, float* __restrict__ part) {
  int b = blockIdx.y;
  int p = blockIdx.x;
  int t = threadIdx.x;  // 256
  float acc[4] = {0.f, 0.f, 0.f, 0.f};
  int s0 = p * 32;
#pragma unroll 4
  for (int s = s0; s < s0 + 32; ++s) {
    float pr = probs[(size_t)b * CTXF + s];
    const float* vrow = (s < SCTX) ? (vcache + ((size_t)b * SCTX + s) * EMBD)
                                   : (vnew + (size_t)b * EMBD);
#pragma unroll
    for (int r = 0; r < 4; ++r) acc[r] = fmaf(pr, vrow[t + r * 256], acc[r]);
  }
#pragma unroll
  for (int r = 0; r < 4; ++r) part[((size_t)p * BATCH + b) * EMBD + t + r * 256] = acc[r];
}

// ---------------- logits ----------------
// split-K=4 variant: grid (256, 4), partials in ws
__global__ void logits_splitk(const float* __restrict__ X, const float* __restrict__ Wl,
                              float* __restrict__ part) {
  int j = blockIdx.x * 256 + threadIdx.x;
  if (j >= VOC) return;
  int p = blockIdx.y;
  float acc[BATCH];
#pragma unroll
  for (int b = 0; b < BATCH; ++b) acc[b] = 0.f;
  int i0 = p * 256;
#pragma unroll 8
  for (int i = i0; i < i0 + 256; ++i) {
    float w = Wl[(size_t)i * VOC + j];
#pragma unroll
    for (int b = 0; b < BATCH; ++b) acc[b] = fmaf(X[b * EMBD + i], w, acc[b]);
  }
#pragma unroll
  for (int b = 0; b < BATCH; ++b) part[((size_t)p * BATCH + b) * VOC + j] = acc[b];
}

__global__ void logits_reduce(const float* __restrict__ part, const float* __restrict__ bl,
                              float* __restrict__ out) {
  size_t m = (size_t)blockIdx.x * 256 + threadIdx.x;
  if (m >= (size_t)BATCH * VOC) return;
  int j = (int)(m % VOC);
  float s = 0.f;
#pragma unroll
  for (int p = 0; p < 4; ++p) s += part[(size_t)p * BATCH * VOC + m];
  out[m] = s + bl[j];
}

// fallback (small ws): split batch in halves, full K, direct write
__global__ void logits_splitb(const float* __restrict__ X, const float* __restrict__ Wl,
                              const float* __restrict__ bl, float* __restrict__ out) {
  int j = blockIdx.x * 256 + threadIdx.x;
  if (j >= VOC) return;
  int b0 = blockIdx.y * 16;
  float acc[16];
#pragma unroll
  for (int b = 0; b < 16; ++b) acc[b] = 0.f;
#pragma unroll 8
  for (int i = 0; i < EMBD; ++i) {
    float w = Wl[(size_t)i * VOC + j];
#pragma unroll
    for (int b = 0; b < 16; ++b) acc[b] = fmaf(X[(b0 + b) * EMBD + i], w, acc[b]);
  }
  float bb = bl[j];
#pragma unroll
  for (int b = 0; b < 16; ++b) out[(size_t)(b0 + b) * VOC + j] = acc[b] + bb;
}

extern "C" void kernel_launch(void* const* d_in, const int* in_sizes, int n_in,
                              void* d_out, int out_size, void* d_ws, size_t ws_size,
                              hipStream_t stream) {
  const int* idx = (const int*)d_in[0];
  const float* key_cache = (const float*)d_in[1];
  const float* value_cache = (const float*)d_in[2];
  const float* emb_table = (const float*)d_in[3];
  const float* pos_table = (const float*)d_in[4];
  const float* Wk = (const float*)d_in[5];
  const float* bk = (const float*)d_in[6];
  const float* Wv = (const float*)d_in[7];
  const float* bv = (const float*)d_in[8];
  const float* Wq = (const float*)d_in[9];
  const float* bq = (const float*)d_in[10];
  const float* W1 = (const float*)d_in[11];
  const float* b1 = (const float*)d_in[12];
  const float* W2 = (const float*)d_in[13];
  const float* b2 = (const float*)d_in[14];
  const float* Wl = (const float*)d_in[15];
  const float* bl = (const float*)d_in[16];
  float* out = (float*)d_out;

  float* ws = (float*)d_ws;
  float* x    = ws;                    // 32768
  float* k    = ws + 32768;
  float* v    = ws + 65536;
  float* q    = ws + 98304;
  float* prob = ws + 131072;           // scores -> probs in place
  float* attn = ws + 163840;
  float* h    = ws + 196608;           // 131072
  float* ffn  = ws + 327680;
  float* part = ws + 360448;

  size_t partCap = (ws_size / 4 > 360448) ? ws_size / 4 - 360448 : 0;

  embed_kernel<<<dim3(BATCH), 256, 0, stream>>>(idx, emb_table, pos_table, x);

  // QKV: prefer 32 K-chunks (384 blocks) if partials fit
  int QC = (partCap >= (size_t)3 * 32 * BATCH * EMBD) ? 32 : 8;
  skgemm_qkv<<<dim3(4, QC, 3), 256, 0, stream>>>(x, Wk, Wv, Wq, part, EMBD / QC);
  reduce_qkv<<<dim3(128, 3), 256, 0, stream>>>(part, QC, bk, bv, bq, k, v, q);

  scores_kernel<<<dim3(64, BATCH), 256, 0, stream>>>(q, key_cache, k, prob);
  softmax_kernel<<<dim3(BATCH), 1024, 0, stream>>>(prob);
  pv_kernel<<<dim3(32, BATCH), 256, 0, stream>>>(prob, value_cache, v, part);
  reduce_ep<<<dim3(128), 256, 0, stream>>>(part, 32, nullptr, attn, BATCH * EMBD, 0, 0);

  int F1C = (partCap >= (size_t)16 * BATCH * HIDD) ? 16 : 8;
  skgemm<BATCH><<<dim3(16, F1C), 256, 0, stream>>>(attn, W1, part, HIDD, EMBD, EMBD / F1C);
  reduce_ep<<<dim3(512), 256, 0, stream>>>(part, F1C, b1, h, BATCH * HIDD, HIDD - 1, 1);

  int F2C = (partCap >= (size_t)64 * BATCH * EMBD) ? 64 : 32;
  skgemm<BATCH><<<dim3(4, F2C), 256, 0, stream>>>(h, W2, part, EMBD, HIDD, HIDD / F2C);
  reduce_ep<<<dim3(128), 256, 0, stream>>>(part, F2C, b2, ffn, BATCH * EMBD, EMBD - 1, 0);

  if (partCap >= (size_t)4 * BATCH * VOC) {
    logits_splitk<<<dim3(256, 4), 256, 0, stream>>>(ffn, Wl, part);
    logits_reduce<<<dim3(8192), 256, 0, stream>>>(part, bl, out);
  } else {
    logits_splitb<<<dim3(256, 2), 256, 0, stream>>>(ffn, Wl, bl, out);
  }
}

// Round 3
// 297.349 us; speedup vs baseline: 2.1800x; 1.2718x over previous
//
#include <hip/hip_runtime.h>
#include <cstddef>

#define BATCH 32
#define EMBD 1024
#define SCTX 1023   // cached positions
#define CTXF 1024   // full context after concat
#define HIDD 4096
#define VOC 65535

// ---------------- embed: x[b] = emb[idx[b]] + pos[0] ----------------
__global__ void embed_kernel(const int* __restrict__ idx, const float* __restrict__ emb,
                             const float* __restrict__ pos, float* __restrict__ x) {
  int b = blockIdx.x, t = threadIdx.x;  // 32 blocks x 256
  const float4* er = (const float4*)(emb + (size_t)idx[b] * EMBD);
  const float4* pr = (const float4*)pos;
  float4 e = er[t], p = pr[t];
  ((float4*)(x + (size_t)b * EMBD))[t] = make_float4(e.x + p.x, e.y + p.y, e.z + p.z, e.w + p.w);
}

// ---------------- split-K skinny GEMM for QKV ----------------
__global__ void skgemm_qkv(const float* __restrict__ X,
                           const float* __restrict__ Wk, const float* __restrict__ Wv,
                           const float* __restrict__ Wq,
                           float* __restrict__ Pout, int chunk) {
  const float* __restrict__ W = (blockIdx.z == 0) ? Wk : (blockIdx.z == 1) ? Wv : Wq;
  int j = blockIdx.x * 256 + threadIdx.x;       // grid.x = 4
  int p = blockIdx.y;
  int nch = gridDim.y;
  float acc[BATCH];
#pragma unroll
  for (int b = 0; b < BATCH; ++b) acc[b] = 0.f;
  int i0 = p * chunk;
#pragma unroll 8
  for (int i = i0; i < i0 + chunk; ++i) {
    float w = W[(size_t)i * EMBD + j];
#pragma unroll
    for (int b = 0; b < BATCH; ++b) acc[b] = fmaf(X[b * EMBD + i], w, acc[b]);
  }
#pragma unroll
  for (int b = 0; b < BATCH; ++b)
    Pout[((size_t)(blockIdx.z * nch + p) * BATCH + b) * EMBD + j] = acc[b];
}

__global__ void reduce_qkv(const float* __restrict__ part, int P,
                           const float* __restrict__ bk, const float* __restrict__ bv,
                           const float* __restrict__ bq,
                           float* __restrict__ kout, float* __restrict__ vout,
                           float* __restrict__ qout) {
  int z = blockIdx.y;
  int m = blockIdx.x * 256 + threadIdx.x;       // < 32768
  float s = 0.f;
  for (int p = 0; p < P; ++p) s += part[(size_t)(z * P + p) * (BATCH * EMBD) + m];
  const float* bias = (z == 0) ? bk : (z == 1) ? bv : bq;
  float* out = (z == 0) ? kout : (z == 1) ? vout : qout;
  out[m] = s + bias[m & (EMBD - 1)];
}

template <int BB>
__global__ void skgemm(const float* __restrict__ X, const float* __restrict__ W,
                       float* __restrict__ Pout, int N, int K, int chunk) {
  int j = blockIdx.x * 256 + threadIdx.x;
  int p = blockIdx.y;
  float acc[BB];
#pragma unroll
  for (int b = 0; b < BB; ++b) acc[b] = 0.f;
  int i0 = p * chunk, i1 = i0 + chunk;
#pragma unroll 8
  for (int i = i0; i < i1; ++i) {
    float w = W[(size_t)i * N + j];
#pragma unroll
    for (int b = 0; b < BB; ++b) acc[b] = fmaf(X[b * K + i], w, acc[b]);
  }
#pragma unroll
  for (int b = 0; b < BB; ++b) Pout[((size_t)p * BB + b) * N + j] = acc[b];
}

// out[m] = act( sum_p part[p][m] + bias[m & mask] )
__global__ void reduce_ep(const float* __restrict__ part, int P,
                          const float* __restrict__ bias, float* __restrict__ out,
                          int total, int mask, int act) {
  int m = blockIdx.x * 256 + threadIdx.x;
  if (m >= total) return;
  float s = 0.f;
  for (int p = 0; p < P; ++p) s += part[(size_t)p * total + m];
  if (bias) s += bias[m & mask];
  if (act == 1) s = 0.5f * s * (1.f + erff(s * 0.70710678118654752f));
  out[m] = s;
}

// ---------------- attention ----------------
// grid (64, 32): block = 4 waves, each wave computes 4 score rows concurrently
__global__ void scores_kernel(const float* __restrict__ q, const float* __restrict__ kcache,
                              const float* __restrict__ knew, float* __restrict__ scores) {
  int b = blockIdx.y;
  int wave = threadIdx.x >> 6, lane = threadIdx.x & 63;
  const float* qb = q + (size_t)b * EMBD;
  float4 qf[4];
#pragma unroll
  for (int r = 0; r < 4; ++r) qf[r] = *(const float4*)(qb + r * 256 + lane * 4);
  int sbase = blockIdx.x * 16 + wave * 4;
  const float* kr[4];
  float acc[4] = {0.f, 0.f, 0.f, 0.f};
#pragma unroll
  for (int it = 0; it < 4; ++it) {
    int s = sbase + it;
    kr[it] = (s < SCTX) ? (kcache + ((size_t)b * SCTX + s) * EMBD)
                        : (knew + (size_t)b * EMBD);
  }
#pragma unroll
  for (int r = 0; r < 4; ++r) {
#pragma unroll
    for (int it = 0; it < 4; ++it) {
      float4 kf = *(const float4*)(kr[it] + r * 256 + lane * 4);
      acc[it] += qf[r].x * kf.x + qf[r].y * kf.y + qf[r].z * kf.z + qf[r].w * kf.w;
    }
  }
#pragma unroll
  for (int it = 0; it < 4; ++it) {
    float a = acc[it];
#pragma unroll
    for (int m = 32; m > 0; m >>= 1) a += __shfl_xor(a, m, 64);
    if (lane == 0) scores[(size_t)b * CTXF + sbase + it] = a * 0.03125f;  // 1/sqrt(1024)
  }
}

__global__ void softmax_kernel(float* __restrict__ sc) {
  int b = blockIdx.x;
  int t = threadIdx.x;  // 1024
  __shared__ float red[16];
  float v = sc[(size_t)b * CTXF + t];
  float m = v;
#pragma unroll
  for (int d = 32; d > 0; d >>= 1) m = fmaxf(m, __shfl_xor(m, d, 64));
  if ((t & 63) == 0) red[t >> 6] = m;
  __syncthreads();
  float bm = red[0];
#pragma unroll
  for (int w = 1; w < 16; ++w) bm = fmaxf(bm, red[w]);
  float e = expf(v - bm);
  __syncthreads();
  float s = e;
#pragma unroll
  for (int d = 32; d > 0; d >>= 1) s += __shfl_xor(s, d, 64);
  if ((t & 63) == 0) red[t >> 6] = s;
  __syncthreads();
  float bs = 0.f;
#pragma unroll
  for (int w = 0; w < 16; ++w) bs += red[w];
  sc[(size_t)b * CTXF + t] = e / bs;
}

// grid (32, 32): 32 chunks of 32 rows
__global__ void pv_kernel(const float* __restrict__ probs, const float* __restrict__ vcache,
                          const float* __restrict__ vnew, float* __restrict__ part) {
  int b = blockIdx.y;
  int p = blockIdx.x;
  int t = threadIdx.x;  // 256
  float acc[4] = {0.f, 0.f, 0.f, 0.f};
  int s0 = p * 32;
#pragma unroll 4
  for (int s = s0; s < s0 + 32; ++s) {
    float pr = probs[(size_t)b * CTXF + s];
    const float* vrow = (s < SCTX) ? (vcache + ((size_t)b * SCTX + s) * EMBD)
                                   : (vnew + (size_t)b * EMBD);
#pragma unroll
    for (int r = 0; r < 4; ++r) acc[r] = fmaf(pr, vrow[t + r * 256], acc[r]);
  }
#pragma unroll
  for (int r = 0; r < 4; ++r) part[((size_t)p * BATCH + b) * EMBD + t + r * 256] = acc[r];
}

// ---------------- logits v3 ----------------
// grid (128, 4), 256 threads. Block covers 512 columns (thread t -> jb+t, jb+256+t),
// K-quarter p (256 i). X chunk staged TRANSPOSED in LDS; inner loop reads it as
// broadcast ds_read_b128, weights as coalesced dword loads.
__global__ __launch_bounds__(256) void logits_v3(const float* __restrict__ X,
                                                 const float* __restrict__ Wl,
                                                 float* __restrict__ part) {
  __shared__ float xt[256][BATCH];  // 32 KB
  int t = threadIdx.x;
  int p = blockIdx.y;
  int q0 = p * 256;
  for (int m = t; m < 256 * BATCH; m += 256) {
    int i = m >> 5, b = m & 31;
    xt[i][b] = X[b * EMBD + q0 + i];
  }
  __syncthreads();

  int jb = blockIdx.x * 512;
  int j0 = jb + t;
  int j1 = jb + 256 + t;
  bool v1 = (j1 < VOC);
  float acc0[BATCH], acc1[BATCH];
#pragma unroll
  for (int b = 0; b < BATCH; ++b) { acc0[b] = 0.f; acc1[b] = 0.f; }

  const float* wp = Wl + (size_t)q0 * VOC;
#pragma unroll 4
  for (int i = 0; i < 256; ++i) {
    float w0 = wp[(size_t)i * VOC + j0];
    float w1 = v1 ? wp[(size_t)i * VOC + j1] : 0.f;
#pragma unroll
    for (int b = 0; b < BATCH; ++b) {
      float xv = xt[i][b];
      acc0[b] = fmaf(xv, w0, acc0[b]);
      acc1[b] = fmaf(xv, w1, acc1[b]);
    }
  }
#pragma unroll
  for (int b = 0; b < BATCH; ++b) {
    part[((size_t)p * BATCH + b) * VOC + j0] = acc0[b];
    if (v1) part[((size_t)p * BATCH + b) * VOC + j1] = acc1[b];
  }
}

__global__ void logits_reduce(const float* __restrict__ part, const float* __restrict__ bl,
                              float* __restrict__ out) {
  size_t m = (size_t)blockIdx.x * 256 + threadIdx.x;
  if (m >= (size_t)BATCH * VOC) return;
  int j = (int)(m % VOC);
  float s = 0.f;
#pragma unroll
  for (int p = 0; p < 4; ++p) s += part[(size_t)p * BATCH * VOC + m];
  out[m] = s + bl[j];
}

// fallback (small ws): split batch in halves, full K, direct write
__global__ void logits_splitb(const float* __restrict__ X, const float* __restrict__ Wl,
                              const float* __restrict__ bl, float* __restrict__ out) {
  int j = blockIdx.x * 256 + threadIdx.x;
  if (j >= VOC) return;
  int b0 = blockIdx.y * 16;
  float acc[16];
#pragma unroll
  for (int b = 0; b < 16; ++b) acc[b] = 0.f;
#pragma unroll 8
  for (int i = 0; i < EMBD; ++i) {
    float w = Wl[(size_t)i * VOC + j];
#pragma unroll
    for (int b = 0; b < 16; ++b) acc[b] = fmaf(X[(b0 + b) * EMBD + i], w, acc[b]);
  }
  float bb = bl[j];
#pragma unroll
  for (int b = 0; b < 16; ++b) out[(size_t)(b0 + b) * VOC + j] = acc[b] + bb;
}

extern "C" void kernel_launch(void* const* d_in, const int* in_sizes, int n_in,
                              void* d_out, int out_size, void* d_ws, size_t ws_size,
                              hipStream_t stream) {
  const int* idx = (const int*)d_in[0];
  const float* key_cache = (const float*)d_in[1];
  const float* value_cache = (const float*)d_in[2];
  const float* emb_table = (const float*)d_in[3];
  const float* pos_table = (const float*)d_in[4];
  const float* Wk = (const float*)d_in[5];
  const float* bk = (const float*)d_in[6];
  const float* Wv = (const float*)d_in[7];
  const float* bv = (const float*)d_in[8];
  const float* Wq = (const float*)d_in[9];
  const float* bq = (const float*)d_in[10];
  const float* W1 = (const float*)d_in[11];
  const float* b1 = (const float*)d_in[12];
  const float* W2 = (const float*)d_in[13];
  const float* b2 = (const float*)d_in[14];
  const float* Wl = (const float*)d_in[15];
  const float* bl = (const float*)d_in[16];
  float* out = (float*)d_out;

  float* ws = (float*)d_ws;
  float* x    = ws;                    // 32768
  float* k    = ws + 32768;
  float* v    = ws + 65536;
  float* q    = ws + 98304;
  float* prob = ws + 131072;           // scores -> probs in place
  float* attn = ws + 163840;
  float* h    = ws + 196608;           // 131072
  float* ffn  = ws + 327680;
  float* part = ws + 360448;

  size_t partCap = (ws_size / 4 > 360448) ? ws_size / 4 - 360448 : 0;

  embed_kernel<<<dim3(BATCH), 256, 0, stream>>>(idx, emb_table, pos_table, x);

  int QC = (partCap >= (size_t)3 * 32 * BATCH * EMBD) ? 32 : 8;
  skgemm_qkv<<<dim3(4, QC, 3), 256, 0, stream>>>(x, Wk, Wv, Wq, part, EMBD / QC);
  reduce_qkv<<<dim3(128, 3), 256, 0, stream>>>(part, QC, bk, bv, bq, k, v, q);

  scores_kernel<<<dim3(64, BATCH), 256, 0, stream>>>(q, key_cache, k, prob);
  softmax_kernel<<<dim3(BATCH), 1024, 0, stream>>>(prob);
  pv_kernel<<<dim3(32, BATCH), 256, 0, stream>>>(prob, value_cache, v, part);
  reduce_ep<<<dim3(128), 256, 0, stream>>>(part, 32, nullptr, attn, BATCH * EMBD, 0, 0);

  int F1C = (partCap >= (size_t)16 * BATCH * HIDD) ? 16 : 8;
  skgemm<BATCH><<<dim3(16, F1C), 256, 0, stream>>>(attn, W1, part, HIDD, EMBD, EMBD / F1C);
  reduce_ep<<<dim3(512), 256, 0, stream>>>(part, F1C, b1, h, BATCH * HIDD, HIDD - 1, 1);

  int F2C = (partCap >= (size_t)64 * BATCH * EMBD) ? 64 : 32;
  skgemm<BATCH><<<dim3(4, F2C), 256, 0, stream>>>(h, W2, part, EMBD, HIDD, HIDD / F2C);
  reduce_ep<<<dim3(128), 256, 0, stream>>>(part, F2C, b2, ffn, BATCH * EMBD, EMBD - 1, 0);

  if (partCap >= (size_t)4 * BATCH * VOC) {
    logits_v3<<<dim3(128, 4), 256, 0, stream>>>(ffn, Wl, part);
    logits_reduce<<<dim3(8192), 256, 0, stream>>>(part, bl, out);
  } else {
    logits_splitb<<<dim3(256, 2), 256, 0, stream>>>(ffn, Wl, bl, out);
  }
}